// Round 9
// baseline (2853.409 us; speedup 1.0000x reference)
//
#include <hip/hip_runtime.h>
#include <math.h>

#define BATCH 16
#define NF_ 400
#define TLEN 204800
#define NMELS 80
#define HID 256
#define SRD 44100.0

// ---- compact lifetime-aliased workspace (floats), S = 1,638,400 ----
// ORDER CONSTRAINT: ir_src (reads ssp) MUST run before ir_noise (writes ir3 over ssp).
static constexpr size_t S_ = 1638400;
static constexpr size_t OFF_COMB = 0;          // [0,2S)   comb: phase -> conv1
static constexpr size_t OFF_H1   = 2 * S_;     // [2S,3S)  h1: conv1x3 -> conv2ln
static constexpr size_t OFF_H2   = 3 * S_;     // [3S,4S)  h2: conv2ln -> proj
static constexpr size_t OFF_IR1  = 2 * S_;     // [2S,3.99S) ir1: ir_allpass -> conv1 (h1,h2 dead)
static constexpr size_t OFF_PHI  = 4 * S_;     // [4S,5S)  phi: proj -> ir_allpass
static constexpr size_t OFF_NSP  = 5 * S_;     // [5S,6S)  nsp: proj -> ir_noise
static constexpr size_t OFF_HTMP = 4 * S_;     // [4S,6S)  harmonic tmp: conv1 -> conv2 (phi,nsp dead)
static constexpr size_t OFF_SRC  = 6 * S_;     // [6S,8S)  ssp: proj -> ir_src
static constexpr size_t OFF_IR3  = 6 * S_;     // [6S,7.99S) ir3: ir_noise -> conv3 (ssp dead AFTER ir_src)
static constexpr size_t OFF_IR2  = 8 * S_;     // [8S,11.99S) ir2: ir_src -> conv2
static constexpr size_t OFF_FSUM = 12 * S_;          // 6400 doubles
static constexpr size_t OFF_PREF = 12 * S_ + 12800;  // 6400 doubles
static constexpr size_t OFF_GN   = 12 * S_ + 25600;  // 128 floats

// f0 upsample with JAX's exact f32 rounding: fl(fl(a*(1-w)) + fl(b*w))
__device__ __forceinline__ float cs7_f0_at(const float* f0f, int b, int n, int k) {
    float a = f0f[b * NF_ + n];
    float c = f0f[b * NF_ + min(n + 1, NF_ - 1)];
    float w = (float)k * (1.0f / 512.0f);          // exact
    return __fadd_rn(__fmul_rn(a, 1.0f - w), __fmul_rn(c, w));
}

__global__ void cs7_fsum(const float* __restrict__ f0f, double* __restrict__ fsum) {
    int gid = blockIdx.x * blockDim.x + threadIdx.x;
    if (gid >= BATCH * NF_) return;
    int b = gid / NF_, n = gid % NF_;
    double s = 0.0;
    for (int k = 0; k < 512; ++k) s += (double)cs7_f0_at(f0f, b, n, k) / SRD;
    fsum[gid] = s;
}

__global__ void cs7_prefix(const double* __restrict__ fsum, double* __restrict__ pref) {
    int b = threadIdx.x;
    if (b >= BATCH) return;
    double run = 0.0;
    for (int n = 0; n < NF_; ++n) { pref[b * NF_ + n] = run; run += fsum[b * NF_ + n]; }
}

// per-frame block: f64 inclusive scan of f0/SR -> x, wrap, sinc combtooth + phase output
__global__ __launch_bounds__(512) void cs7_phase(const float* __restrict__ f0f,
        const float* __restrict__ ip, const double* __restrict__ pref,
        float* __restrict__ comb, float* __restrict__ phase_out) {
    __shared__ double sc[512];
    int b = blockIdx.x / NF_, n = blockIdx.x % NF_;
    int k = threadIdx.x;
    float f0 = cs7_f0_at(f0f, b, n, k);
    sc[k] = (double)f0 / SRD;
    __syncthreads();
    for (int off = 1; off < 512; off <<= 1) {
        double v = (k >= off) ? sc[k - off] : 0.0;
        __syncthreads();
        sc[k] += v;
        __syncthreads();
    }
    double xd = pref[b * NF_ + n] + sc[k] + (double)ip[b] / (2.0 * M_PI);
    xd -= rint(xd);                      // round-half-even, matches jnp.round
    float xf = (float)xd;                // reference casts x to f32 before sinc
    double zd = 44100.0 * (double)xf / ((double)f0 + 0.001);
    double pz = M_PI * zd;
    comb[(size_t)b * TLEN + n * 512 + k] = (zd == 0.0) ? 1.0f : (float)(sin(pz) / pz);
    if (k == 0) phase_out[b * NF_ + n] = (float)(2.0 * M_PI * (double)xf);
}

__global__ __launch_bounds__(256) void cs7_conv1x3(const float* __restrict__ mel,
        const float* __restrict__ w1, const float* __restrict__ b1, float* __restrict__ h1) {
    __shared__ float m3[3][NMELS];
    int b = blockIdx.x / NF_, l = blockIdx.x % NF_;
    int tid = threadIdx.x;
    for (int i = tid; i < 3 * NMELS; i += 256) {
        int tap = i / NMELS, ic = i % NMELS;
        int li = l + tap - 1;
        m3[tap][ic] = (li >= 0 && li < NF_) ? mel[((size_t)b * NF_ + li) * NMELS + ic] : 0.0f;
    }
    __syncthreads();
    int oc = tid;
    double acc = (double)b1[oc];
    const float* wp = w1 + (size_t)oc * NMELS * 3;
    for (int ic = 0; ic < NMELS; ++ic)
        acc += (double)m3[0][ic] * (double)wp[ic * 3]
             + (double)m3[1][ic] * (double)wp[ic * 3 + 1]
             + (double)m3[2][ic] * (double)wp[ic * 3 + 2];
    h1[((size_t)b * NF_ + l) * HID + oc] = (float)acc;
}

__global__ __launch_bounds__(256) void cs7_gnstats(const float* __restrict__ h1, float* __restrict__ gn) {
    __shared__ double rs[256], rq[256];
    int b = blockIdx.x >> 2, g = blockIdx.x & 3;
    int tid = threadIdx.x;
    double s = 0.0, q = 0.0;
    for (int i = tid; i < 64 * NF_; i += 256) {
        int l = i >> 6, c = g * 64 + (i & 63);
        float v = h1[((size_t)b * NF_ + l) * HID + c];
        s += v; q += (double)v * v;
    }
    rs[tid] = s; rq[tid] = q;
    __syncthreads();
    for (int off = 128; off > 0; off >>= 1) {
        if (tid < off) { rs[tid] += rs[tid + off]; rq[tid] += rq[tid + off]; }
        __syncthreads();
    }
    if (tid == 0) {
        double mu = rs[0] / (64.0 * NF_);
        double var = rq[0] / (64.0 * NF_) - mu * mu;
        gn[blockIdx.x * 2] = (float)mu;
        gn[blockIdx.x * 2 + 1] = (float)(1.0 / sqrt(var + 1e-5));
    }
}

// GN-affine + lrelu + conv2 + positional-enc + LayerNorm (f64 accumulation), 8 columns per block
__global__ __launch_bounds__(256) void cs7_conv2ln(const float* __restrict__ h1,
        const float* __restrict__ gn, const float* __restrict__ gng, const float* __restrict__ gnb,
        const float* __restrict__ w2, const float* __restrict__ b2,
        const float* __restrict__ pw, const float* __restrict__ pb,
        const float* __restrict__ lng, const float* __restrict__ lnb,
        const float* __restrict__ phase, float* __restrict__ h2) {
    __shared__ float cols[10][HID];
    __shared__ double rsum[256], rsq[256];
    int b = blockIdx.x / 50, l0 = (blockIdx.x % 50) * 8;
    int tid = threadIdx.x;
    for (int i = tid; i < 10 * HID; i += 256) {
        int lc = i >> 8, c = i & 255;
        int l = l0 + lc - 1;
        float v = 0.0f;
        if (l >= 0 && l < NF_) {
            float hv = h1[((size_t)b * NF_ + l) * HID + c];
            int g = c >> 6;
            double vv = ((double)hv - (double)gn[(b * 4 + g) * 2]) * (double)gn[(b * 4 + g) * 2 + 1]
                        * (double)gng[c] + (double)gnb[c];
            v = (float)(vv >= 0.0 ? vv : 0.01 * vv);
        }
        cols[lc][c] = v;
    }
    __syncthreads();
    int oc = tid;
    double acc[8];
    #pragma unroll
    for (int lt = 0; lt < 8; ++lt) acc[lt] = (double)b2[oc];
    const float* wp = w2 + (size_t)oc * HID * 3;
    for (int ic = 0; ic < HID; ++ic) {
        double w0 = (double)wp[ic * 3], w1v = (double)wp[ic * 3 + 1], w2v = (double)wp[ic * 3 + 2];
        float cc[10];
        #pragma unroll
        for (int j = 0; j < 10; ++j) cc[j] = cols[j][ic];   // broadcast reads
        #pragma unroll
        for (int lt = 0; lt < 8; ++lt)
            acc[lt] += (double)cc[lt] * w0 + (double)cc[lt + 1] * w1v + (double)cc[lt + 2] * w2v;
    }
    for (int lt = 0; lt < 8; ++lt) {
        int l = l0 + lt;
        double ph = (double)phase[b * NF_ + l];
        double sp, cp; sincos(ph, &sp, &cp);
        double v = acc[lt] + sp * (double)pw[oc * 2] + cp * (double)pw[oc * 2 + 1] + (double)pb[oc];
        rsum[tid] = v; rsq[tid] = v * v;
        __syncthreads();
        for (int off = 128; off > 0; off >>= 1) {
            if (tid < off) { rsum[tid] += rsum[tid + off]; rsq[tid] += rsq[tid + off]; }
            __syncthreads();
        }
        double mu = rsum[0] * (1.0 / 256.0);
        double var = rsq[0] * (1.0 / 256.0) - mu * mu;
        double rstd = 1.0 / sqrt(var + 1e-5);
        __syncthreads();
        h2[((size_t)b * NF_ + l) * HID + oc] = (float)((v - mu) * rstd * (double)lng[oc] + (double)lnb[oc]);
    }
}

// 1024-wide projection (f64) + split: phi = cumsum(pi*tanh(gd)), exp(hm), exp(nm)/128
__global__ __launch_bounds__(256) void cs7_proj(const float* __restrict__ h2,
        const float* __restrict__ ow, const float* __restrict__ ob,
        float* __restrict__ phi, float* __restrict__ srcspec, float* __restrict__ nspec) {
    __shared__ float hrow[8][HID];
    __shared__ double ssc[256];
    int b = blockIdx.x / 50, l0 = (blockIdx.x % 50) * 8;
    int tid = threadIdx.x;
    for (int i = tid; i < 8 * HID; i += 256) {
        int lc = i >> 8, c = i & 255;
        hrow[lc][c] = h2[((size_t)b * NF_ + l0 + lc) * HID + c];
    }
    __syncthreads();
    double a0[8], a1[8], a2[8], a3[8];
    #pragma unroll
    for (int lt = 0; lt < 8; ++lt) {
        a0[lt] = (double)ob[tid];       a1[lt] = (double)ob[256 + tid];
        a2[lt] = (double)ob[512 + tid]; a3[lt] = (double)ob[768 + tid];
    }
    const float* w0p = ow + (size_t)tid * HID;
    const float* w1p = ow + (size_t)(256 + tid) * HID;
    const float* w2p = ow + (size_t)(512 + tid) * HID;
    const float* w3p = ow + (size_t)(768 + tid) * HID;
    for (int ic = 0; ic < HID; ++ic) {
        double w0 = (double)w0p[ic], w1v = (double)w1p[ic], w2v = (double)w2p[ic], w3v = (double)w3p[ic];
        #pragma unroll
        for (int lt = 0; lt < 8; ++lt) {
            double h = (double)hrow[lt][ic];
            a0[lt] += h * w0; a1[lt] += h * w1v; a2[lt] += h * w2v; a3[lt] += h * w3v;
        }
    }
    for (int lt = 0; lt < 8; ++lt) {
        size_t bl = (size_t)b * NF_ + (l0 + lt);
        double gdv = M_PI * tanh(a0[lt]);
        ssc[tid] = gdv;
        __syncthreads();
        for (int off = 1; off < 256; off <<= 1) {
            double v = (tid >= off) ? ssc[tid - off] : 0.0;
            __syncthreads();
            ssc[tid] += v;
            __syncthreads();
        }
        phi[bl * 256 + tid] = (float)ssc[tid];
        __syncthreads();
        srcspec[bl * 512 + tid] = (float)exp(a1[lt]);
        srcspec[bl * 512 + 256 + tid] = (float)exp(a2[lt]);
        nspec[bl * 256 + tid] = (float)(exp(a3[lt]) * (1.0 / 128.0));
    }
}

// allpass IR: irfft(exp(i*phi)) (510) rolled by 255. f32 rotation + f64 carrier reseed /16.
__global__ __launch_bounds__(256) void cs7_ir_allpass(const float* __restrict__ phi, float* __restrict__ ir1) {
    __shared__ float cph[256], sph[256];
    size_t bl = blockIdx.x;
    int tid = threadIdx.x;
    {
        float ph = phi[bl * 256 + tid];
        cph[tid] = 2.0f * cosf(ph); sph[tid] = 2.0f * sinf(ph);   // pre-doubled
    }
    __syncthreads();
    for (int t = tid; t < 510; t += 256) {
        double ang = 2.0 * M_PI * (double)t / 510.0;
        double srd_, crd; sincos(ang, &srd_, &crd);
        double sj, cj;    sincos(16.0 * ang, &sj, &cj);
        float crf = (float)crd, srf = (float)srd_;
        double cD = crd, sD = srd_;
        float acc = 0.5f * (cph[0] + ((t & 1) ? -cph[255] : cph[255]));
        for (int k0 = 1; k0 <= 254; k0 += 16) {
            float c = (float)cD, s = (float)sD;
            int ke = min(k0 + 16, 255);
            for (int k = k0; k < ke; ++k) {
                acc += cph[k] * c - sph[k] * s;
                float cn = c * crf - s * srf;
                float sn = s * crf + c * srf;
                c = cn; s = sn;
            }
            double nc = cD * cj - sD * sj;
            double ns = sD * cj + cD * sj;
            cD = nc; sD = ns;
        }
        int j = t + 255; if (j >= 510) j -= 510;
        ir1[bl * 510 + j] = acc * (1.0f / 510.0f);
    }
}

// src IR window — REFERENCE SEMANTICS: w=(j-511)/hw; if (w>1) w:=0 (ARGUMENT zeroed -> win 1!)
__device__ __forceinline__ float cs7_hw_win(int j, float hw) {
    float wv = (float)(j - 511) / hw;
    if (wv > 1.0f) wv = 0.0f;
    return (1.0f + cosf((float)M_PI * wv)) * 0.5f;
}

// src IR: irfft(real exp(hm)) (1022), roll 511. f32 rotation + f64 carrier reseed /16.
__global__ __launch_bounds__(256) void cs7_ir_src(const float* __restrict__ srcspec,
        const float* __restrict__ f0f, float* __restrict__ ir2) {
    __shared__ float sp[512];
    size_t bl = blockIdx.x;
    int b = blockIdx.x / NF_, l = blockIdx.x % NF_;
    int tid = threadIdx.x;
    sp[tid] = 2.0f * srcspec[bl * 512 + tid];
    sp[tid + 256] = 2.0f * srcspec[bl * 512 + 256 + tid];
    __syncthreads();
    float hw = 66150.0f / (f0f[b * NF_ + l] + 0.001f);
    for (int t = tid; t < 512; t += 256) {
        double ang = 2.0 * M_PI * (double)t / 1022.0;
        double srd_, crd; sincos(ang, &srd_, &crd);
        double sj, cj;    sincos(16.0 * ang, &sj, &cj);
        float crf = (float)crd, srf = (float)srd_;
        double cD = crd, sD = srd_;
        float acc = 0.5f * (sp[0] + ((t & 1) ? -sp[511] : sp[511]));
        for (int k0 = 1; k0 <= 510; k0 += 16) {
            float c = (float)cD, s = (float)sD;
            int ke = min(k0 + 16, 511);
            for (int k = k0; k < ke; ++k) {
                acc += sp[k] * c;
                float cn = c * crf - s * srf;
                float sn = s * crf + c * srf;
                c = cn; s = sn;
            }
            double nc = cD * cj - sD * sj;
            double ns = sD * cj + cD * sj;
            cD = nc; sD = ns;
        }
        float raw = acc * (1.0f / 1022.0f);
        {
            int j = t + 511; if (j >= 1022) j -= 1022;
            ir2[bl * 1022 + j] = raw * cs7_hw_win(j, hw);
        }
        if (t >= 1 && t <= 510) {          // even symmetry: raw[1022-t] == raw[t]
            int j = 511 - t;
            ir2[bl * 1022 + j] = raw * cs7_hw_win(j, hw);
        }
    }
}

// noise IR: irfft(real exp(nm)/128) (510): ir[j] = raw[(j-255)%510]*hann_p[j]. f32+reseed.
__global__ __launch_bounds__(256) void cs7_ir_noise(const float* __restrict__ nspec, float* __restrict__ ir3) {
    __shared__ float sp[256];
    size_t bl = blockIdx.x;
    int t = threadIdx.x;
    sp[t] = 2.0f * nspec[bl * 256 + t];
    __syncthreads();
    double ang = 2.0 * M_PI * (double)t / 510.0;
    double srd_, crd; sincos(ang, &srd_, &crd);
    double sj, cj;    sincos(16.0 * ang, &sj, &cj);
    float crf = (float)crd, srf = (float)srd_;
    double cD = crd, sD = srd_;
    float acc = 0.5f * (sp[0] + ((t & 1) ? -sp[255] : sp[255]));
    for (int k0 = 1; k0 <= 254; k0 += 16) {
        float c = (float)cD, s = (float)sD;
        int ke = min(k0 + 16, 255);
        for (int k = k0; k < ke; ++k) {
            acc += sp[k] * c;
            float cn = c * crf - s * srf;
            float sn = s * crf + c * srf;
            c = cn; s = sn;
        }
        double nc = cD * cj - sD * sj;
        double ns = sD * cj + cD * sj;
        cD = nc; sD = ns;
    }
    float raw = acc * (1.0f / 510.0f);
    {
        int j = t + 255; if (j >= 510) j -= 510;
        float win = 0.5f - 0.5f * cosf((float)(2.0 * M_PI) * (float)j / 510.0f);
        ir3[bl * 510 + j] = raw * win;
    }
    if (t >= 1 && t <= 254) {              // symmetry partner 510-t
        int j = 255 - t;
        float win = 0.5f - 0.5f * cosf((float)(2.0 * M_PI) * (float)j / 510.0f);
        ir3[bl * 510 + j] = raw * win;
    }
}

// ---------------------------------------------------------------------------
// Windowed OLA convolution, conflict-free version:
//  - IR staged REVERSED into LDS (sir[x] = ir[IRS-1+PAD-x]) so per-lane reads
//    ascend; read as aligned float4 (ds_read_b128, lanes @16B stride = no conflicts).
//  - Frame read is wave-uniform broadcast float4 (k-bounds wave-uniform via
//    lane-0 d0; +-PAD zero padding absorbs the <=255 lane spread + alignment).
//  - Inner loop: 16 FMA + 2 b128 reads per 4 taps, no register shuffling movs.
// acc_a (output tb+a) += fr[k] * ir[d0+a-k], d0 = t0+tid*4+512-(m<<9) (==0 mod 4).
// x = IRS-1+PAD - (d0+a-k); chunks start at k==2 (mod 4) so offsets are 16B-aligned.
// ---------------------------------------------------------------------------
template<int IRS, int NFRM, int MOFF>
__global__ __launch_bounds__(256) void cs7_conv(const float* __restrict__ audio,
        const float* __restrict__ ir, float* __restrict__ out, float scale, float shift) {
    constexpr int PAD = 264;
    constexpr int W   = (IRS + 2 * PAD + 3) & ~3;   // sir row width (16B aligned rows)
    constexpr int FRW = 1040;                       // fr row: [0..5]=0, [6+k] k in [0,1023], tail 0
    __shared__ float4 sir4[NFRM][W / 4];
    __shared__ float4 fr4[NFRM][FRW / 4];
    float* sir = (float*)sir4;
    float* frp = (float*)fr4;
    int b = blockIdx.x / 200, q = blockIdx.x % 200;
    int t0 = q * 1024;
    int m_lo = 2 * q + MOFF;
    int tid = threadIdx.x;

    // stage frames (single pass incl. zero pads)
    for (int i = tid; i < NFRM * FRW; i += 256) {
        int fi = i / FRW, kk = i - fi * FRW;
        int k = kk - 6;
        float sv = 0.0f;
        if (k >= 0 && k < 1024) {
            int m = m_lo + fi;
            int idx = (m << 9) + k - 512;
            float v = 0.0f;
            if (m >= 0 && m <= 400 && idx >= 0 && idx < TLEN)
                v = audio[(size_t)b * TLEN + idx] * scale + shift;
            float bart = 1.0f - fabsf((float)k * (1.0f / 512.0f) - 1.0f);
            sv = v * bart;
        }
        frp[fi * FRW + kk] = sv;
    }
    // stage reversed IR (single pass incl. zero pads)
    for (int i = tid; i < NFRM * W; i += 256) {
        int fi = i / W, x = i - fi * W;
        int j = (IRS - 1 + PAD) - x;
        int m = m_lo + fi;
        float v = 0.0f;
        if (j >= 0 && j < IRS && m >= 0 && m <= 400)
            v = ir[((size_t)b * NF_ + min(m, 399)) * IRS + j];
        sir[fi * W + x] = v;
    }
    __syncthreads();

    int tb = t0 + tid * 4;
    int wtid0 = tid & ~63;                 // first tid of this wave
    float acc0 = 0, acc1 = 0, acc2 = 0, acc3 = 0;
    #pragma unroll
    for (int fi = 0; fi < NFRM; ++fi) {
        int m = m_lo + fi;
        if (m < 0 || m > 400) continue;                    // block-uniform
        int d0w = t0 + wtid0 * 4 + 512 - (m << 9);         // wave-uniform lane-0 d0
        int klo = max(0, d0w - (IRS - 1));
        int khi = min(1023, d0w + 255);
        if (klo > khi) continue;                           // wave-uniform
        int kc0 = (((klo - 2) & ~3) + 2);                  // ==2 mod 4, in [klo-3, klo]
        int nch = ((khi - kc0) >> 2) + 1;
        int d0  = t0 + tid * 4 + 512 - (m << 9);           // per-lane
        const float4* sp = (const float4*)(sir + fi * W + ((IRS + PAD - 4) - d0 + kc0));
        const float4* fp = (const float4*)(frp + fi * FRW + 6 + kc0);
        float4 A = sp[0];
        for (int c = 0; c < nch; ++c) {
            float4 B = sp[c + 1];
            float4 F = fp[c];
            acc3 += F.x * A.x; acc2 += F.x * A.y; acc1 += F.x * A.z; acc0 += F.x * A.w;
            acc3 += F.y * A.y; acc2 += F.y * A.z; acc1 += F.y * A.w; acc0 += F.y * B.x;
            acc3 += F.z * A.z; acc2 += F.z * A.w; acc1 += F.z * B.x; acc0 += F.z * B.y;
            acc3 += F.w * A.w; acc2 += F.w * B.x; acc1 += F.w * B.y; acc0 += F.w * B.z;
            A = B;
        }
    }
    *(float4*)(out + (size_t)b * TLEN + tb) = make_float4(acc0, acc1, acc2, acc3);
}

__global__ void cs7_add(const float* __restrict__ a, const float* __restrict__ b,
                        float* __restrict__ o, int n4) {
    int i = blockIdx.x * blockDim.x + threadIdx.x;
    if (i < n4) {
        float4 x = ((const float4*)a)[i];
        float4 y = ((const float4*)b)[i];
        ((float4*)o)[i] = make_float4(x.x + y.x, x.y + y.y, x.z + y.z, x.w + y.w);
    }
}

extern "C" void kernel_launch(void* const* d_in, const int* in_sizes, int n_in,
                              void* d_out, int out_size, void* d_ws, size_t ws_size,
                              hipStream_t stream) {
    const float* mel   = (const float*)d_in[0];
    const float* f0f   = (const float*)d_in[1];
    const float* ip    = (const float*)d_in[2];
    const float* unoi  = (const float*)d_in[3];
    const float* w1    = (const float*)d_in[4];
    const float* b1    = (const float*)d_in[5];
    const float* gng   = (const float*)d_in[6];
    const float* gnb   = (const float*)d_in[7];
    const float* w2    = (const float*)d_in[8];
    const float* b2    = (const float*)d_in[9];
    const float* pw    = (const float*)d_in[10];
    const float* pb    = (const float*)d_in[11];
    const float* lng   = (const float*)d_in[12];
    const float* lnb   = (const float*)d_in[13];
    const float* ow    = (const float*)d_in[14];
    const float* ob    = (const float*)d_in[15];
    float* out = (float*)d_out;
    float* ws  = (float*)d_ws;

    float*  comb = ws + OFF_COMB;
    float*  h1   = ws + OFF_H1;
    float*  h2   = ws + OFF_H2;
    float*  ir1  = ws + OFF_IR1;
    float*  phi  = ws + OFF_PHI;
    float*  nsp  = ws + OFF_NSP;
    float*  htmp = ws + OFF_HTMP;
    float*  ssp  = ws + OFF_SRC;
    float*  ir3  = ws + OFF_IR3;
    float*  ir2  = ws + OFF_IR2;
    double* fsum = (double*)(ws + OFF_FSUM);
    double* pref = (double*)(ws + OFF_PREF);
    float*  gn   = ws + OFF_GN;

    float* out_sig   = out;
    float* out_phase = out + (size_t)BATCH * TLEN;
    float* out_harm  = out_phase + BATCH * NF_;
    float* out_noise = out_harm + (size_t)BATCH * TLEN;

    cs7_fsum<<<25, 256, 0, stream>>>(f0f, fsum);
    cs7_prefix<<<1, 16, 0, stream>>>(fsum, pref);
    cs7_phase<<<BATCH * NF_, 512, 0, stream>>>(f0f, ip, pref, comb, out_phase);
    cs7_conv1x3<<<BATCH * NF_, 256, 0, stream>>>(mel, w1, b1, h1);
    cs7_gnstats<<<64, 256, 0, stream>>>(h1, gn);
    cs7_conv2ln<<<BATCH * 50, 256, 0, stream>>>(h1, gn, gng, gnb, w2, b2, pw, pb, lng, lnb, out_phase, h2);
    cs7_proj<<<BATCH * 50, 256, 0, stream>>>(h2, ow, ob, phi, ssp, nsp);
    cs7_ir_allpass<<<BATCH * NF_, 256, 0, stream>>>(phi, ir1);
    cs7_ir_src<<<BATCH * NF_, 256, 0, stream>>>(ssp, f0f, ir2);      // MUST precede ir_noise (ssp/ir3 alias)
    cs7_ir_noise<<<BATCH * NF_, 256, 0, stream>>>(nsp, ir3);
    cs7_conv<510, 4, -1><<<BATCH * 200, 256, 0, stream>>>(comb, ir1, htmp, 1.0f, 0.0f);
    cs7_conv<1022, 5, -2><<<BATCH * 200, 256, 0, stream>>>(htmp, ir2, out_harm, 1.0f, 0.0f);
    cs7_conv<510, 4, -1><<<BATCH * 200, 256, 0, stream>>>(unoi, ir3, out_noise, 2.0f, -1.0f);
    cs7_add<<<(BATCH * TLEN / 4 + 255) / 256, 256, 0, stream>>>(out_harm, out_noise, out_sig, BATCH * TLEN / 4);
}

// Round 10
// 2819.028 us; speedup vs baseline: 1.0122x; 1.0122x over previous
//
#include <hip/hip_runtime.h>
#include <math.h>

#define BATCH 16
#define NF_ 400
#define TLEN 204800
#define NMELS 80
#define HID 256
#define SRD 44100.0

// ---- workspace layout (floats) ----
// Timeline: memset(frA); phase->frA(comb frames)+out_phase; conv1x3->h1; gnstats;
// conv2ln->h2; proj->phi,ssp,nsp; ir_allpass phi->ir1; ir_noise nsp->ir3;
// stagef unoi->frJ; conv3 frJ x ir3 -> out_noise; memset(frJ);
// conv1 frA x ir1 -> frJ (htmp FRAMES); ir_src ssp->ir2(@A, frA dead);
// conv2 frJ x ir2 -> out_harm; add.
static constexpr size_t S_   = 1638400;
static constexpr size_t FRSZ = (size_t)6416 * 1028;        // 6,595,648 (16*401 rows x 1028)
static constexpr size_t OFF_A    = 0;                      // frA (comb frames), later ir2
static constexpr size_t OFF_JN   = FRSZ;                   // h1/h2/phi/nsp early, then frJ
static constexpr size_t OFF_SSP  = 2 * FRSZ;               // ssp survives until ir_src
static constexpr size_t OFF_IR1  = OFF_SSP + 2 * S_;
static constexpr size_t OFF_IR3  = OFF_IR1 + 3264000;
static constexpr size_t OFF_FSUM = OFF_IR3 + 3264000;
static constexpr size_t OFF_PREF = OFF_FSUM + 12800;
static constexpr size_t OFF_GN   = OFF_PREF + 12800;
// total = OFF_GN + 128 = 23,021,824 floats = 92.1 MB

// f0 upsample with JAX's exact f32 rounding: fl(fl(a*(1-w)) + fl(b*w))
__device__ __forceinline__ float cs8_f0_at(const float* f0f, int b, int n, int k) {
    float a = f0f[b * NF_ + n];
    float c = f0f[b * NF_ + min(n + 1, NF_ - 1)];
    float w = (float)k * (1.0f / 512.0f);
    return __fadd_rn(__fmul_rn(a, 1.0f - w), __fmul_rn(c, w));
}

__global__ void cs8_fsum(const float* __restrict__ f0f, double* __restrict__ fsum) {
    int gid = blockIdx.x * blockDim.x + threadIdx.x;
    if (gid >= BATCH * NF_) return;
    int b = gid / NF_, n = gid % NF_;
    double s = 0.0;
    for (int k = 0; k < 512; ++k) s += (double)cs8_f0_at(f0f, b, n, k) / SRD;
    fsum[gid] = s;
}

__global__ void cs8_prefix(const double* __restrict__ fsum, double* __restrict__ pref) {
    int b = threadIdx.x;
    if (b >= BATCH) return;
    double run = 0.0;
    for (int n = 0; n < NF_; ++n) { pref[b * NF_ + n] = run; run += fsum[b * NF_ + n]; }
}

// f64 scan -> x, wrap, sinc combtooth written directly as BART-WINDOWED FRAMES.
// sample s = n*512+k lands in frame m=n at k+512 (bart 1-k/512) and m=n+1 at k (bart k/512).
// frA edge slots (m=0 low half, m=400 high half, k>=1024) are pre-zeroed by memset.
__global__ __launch_bounds__(512) void cs8_phase(const float* __restrict__ f0f,
        const float* __restrict__ ip, const double* __restrict__ pref,
        float* __restrict__ frA, float* __restrict__ phase_out) {
    __shared__ double sc[512];
    int b = blockIdx.x / NF_, n = blockIdx.x % NF_;
    int k = threadIdx.x;
    float f0 = cs8_f0_at(f0f, b, n, k);
    sc[k] = (double)f0 / SRD;
    __syncthreads();
    for (int off = 1; off < 512; off <<= 1) {
        double v = (k >= off) ? sc[k - off] : 0.0;
        __syncthreads();
        sc[k] += v;
        __syncthreads();
    }
    double xd = pref[b * NF_ + n] + sc[k] + (double)ip[b] / (2.0 * M_PI);
    xd -= rint(xd);
    float xf = (float)xd;
    double zd = 44100.0 * (double)xf / ((double)f0 + 0.001);
    double pz = M_PI * zd;
    float cv = (zd == 0.0) ? 1.0f : (float)(sin(pz) / pz);
    float wb = (float)k * (1.0f / 512.0f);
    size_t row = (size_t)(b * 401 + n) * 1028;
    frA[row + 512 + k]  = cv * (1.0f - wb);
    frA[row + 1028 + k] = cv * wb;
    if (k == 0) phase_out[b * NF_ + n] = (float)(2.0 * M_PI * (double)xf);
}

__global__ __launch_bounds__(256) void cs8_conv1x3(const float* __restrict__ mel,
        const float* __restrict__ w1, const float* __restrict__ b1, float* __restrict__ h1) {
    __shared__ float m3[3][NMELS];
    int b = blockIdx.x / NF_, l = blockIdx.x % NF_;
    int tid = threadIdx.x;
    for (int i = tid; i < 3 * NMELS; i += 256) {
        int tap = i / NMELS, ic = i % NMELS;
        int li = l + tap - 1;
        m3[tap][ic] = (li >= 0 && li < NF_) ? mel[((size_t)b * NF_ + li) * NMELS + ic] : 0.0f;
    }
    __syncthreads();
    int oc = tid;
    double acc = (double)b1[oc];
    const float* wp = w1 + (size_t)oc * NMELS * 3;
    for (int ic = 0; ic < NMELS; ++ic)
        acc += (double)m3[0][ic] * (double)wp[ic * 3]
             + (double)m3[1][ic] * (double)wp[ic * 3 + 1]
             + (double)m3[2][ic] * (double)wp[ic * 3 + 2];
    h1[((size_t)b * NF_ + l) * HID + oc] = (float)acc;
}

__global__ __launch_bounds__(256) void cs8_gnstats(const float* __restrict__ h1, float* __restrict__ gn) {
    __shared__ double rs[256], rq[256];
    int b = blockIdx.x >> 2, g = blockIdx.x & 3;
    int tid = threadIdx.x;
    double s = 0.0, q = 0.0;
    for (int i = tid; i < 64 * NF_; i += 256) {
        int l = i >> 6, c = g * 64 + (i & 63);
        float v = h1[((size_t)b * NF_ + l) * HID + c];
        s += v; q += (double)v * v;
    }
    rs[tid] = s; rq[tid] = q;
    __syncthreads();
    for (int off = 128; off > 0; off >>= 1) {
        if (tid < off) { rs[tid] += rs[tid + off]; rq[tid] += rq[tid + off]; }
        __syncthreads();
    }
    if (tid == 0) {
        double mu = rs[0] / (64.0 * NF_);
        double var = rq[0] / (64.0 * NF_) - mu * mu;
        gn[blockIdx.x * 2] = (float)mu;
        gn[blockIdx.x * 2 + 1] = (float)(1.0 / sqrt(var + 1e-5));
    }
}

__global__ __launch_bounds__(256) void cs8_conv2ln(const float* __restrict__ h1,
        const float* __restrict__ gn, const float* __restrict__ gng, const float* __restrict__ gnb,
        const float* __restrict__ w2, const float* __restrict__ b2,
        const float* __restrict__ pw, const float* __restrict__ pb,
        const float* __restrict__ lng, const float* __restrict__ lnb,
        const float* __restrict__ phase, float* __restrict__ h2) {
    __shared__ float cols[10][HID];
    __shared__ double rsum[256], rsq[256];
    int b = blockIdx.x / 50, l0 = (blockIdx.x % 50) * 8;
    int tid = threadIdx.x;
    for (int i = tid; i < 10 * HID; i += 256) {
        int lc = i >> 8, c = i & 255;
        int l = l0 + lc - 1;
        float v = 0.0f;
        if (l >= 0 && l < NF_) {
            float hv = h1[((size_t)b * NF_ + l) * HID + c];
            int g = c >> 6;
            double vv = ((double)hv - (double)gn[(b * 4 + g) * 2]) * (double)gn[(b * 4 + g) * 2 + 1]
                        * (double)gng[c] + (double)gnb[c];
            v = (float)(vv >= 0.0 ? vv : 0.01 * vv);
        }
        cols[lc][c] = v;
    }
    __syncthreads();
    int oc = tid;
    double acc[8];
    #pragma unroll
    for (int lt = 0; lt < 8; ++lt) acc[lt] = (double)b2[oc];
    const float* wp = w2 + (size_t)oc * HID * 3;
    for (int ic = 0; ic < HID; ++ic) {
        double w0 = (double)wp[ic * 3], w1v = (double)wp[ic * 3 + 1], w2v = (double)wp[ic * 3 + 2];
        float cc[10];
        #pragma unroll
        for (int j = 0; j < 10; ++j) cc[j] = cols[j][ic];
        #pragma unroll
        for (int lt = 0; lt < 8; ++lt)
            acc[lt] += (double)cc[lt] * w0 + (double)cc[lt + 1] * w1v + (double)cc[lt + 2] * w2v;
    }
    for (int lt = 0; lt < 8; ++lt) {
        int l = l0 + lt;
        double ph = (double)phase[b * NF_ + l];
        double sp, cp; sincos(ph, &sp, &cp);
        double v = acc[lt] + sp * (double)pw[oc * 2] + cp * (double)pw[oc * 2 + 1] + (double)pb[oc];
        rsum[tid] = v; rsq[tid] = v * v;
        __syncthreads();
        for (int off = 128; off > 0; off >>= 1) {
            if (tid < off) { rsum[tid] += rsum[tid + off]; rsq[tid] += rsq[tid + off]; }
            __syncthreads();
        }
        double mu = rsum[0] * (1.0 / 256.0);
        double var = rsq[0] * (1.0 / 256.0) - mu * mu;
        double rstd = 1.0 / sqrt(var + 1e-5);
        __syncthreads();
        h2[((size_t)b * NF_ + l) * HID + oc] = (float)((v - mu) * rstd * (double)lng[oc] + (double)lnb[oc]);
    }
}

__global__ __launch_bounds__(256) void cs8_proj(const float* __restrict__ h2,
        const float* __restrict__ ow, const float* __restrict__ ob,
        float* __restrict__ phi, float* __restrict__ srcspec, float* __restrict__ nspec) {
    __shared__ float hrow[8][HID];
    __shared__ double ssc[256];
    int b = blockIdx.x / 50, l0 = (blockIdx.x % 50) * 8;
    int tid = threadIdx.x;
    for (int i = tid; i < 8 * HID; i += 256) {
        int lc = i >> 8, c = i & 255;
        hrow[lc][c] = h2[((size_t)b * NF_ + l0 + lc) * HID + c];
    }
    __syncthreads();
    double a0[8], a1[8], a2[8], a3[8];
    #pragma unroll
    for (int lt = 0; lt < 8; ++lt) {
        a0[lt] = (double)ob[tid];       a1[lt] = (double)ob[256 + tid];
        a2[lt] = (double)ob[512 + tid]; a3[lt] = (double)ob[768 + tid];
    }
    const float* w0p = ow + (size_t)tid * HID;
    const float* w1p = ow + (size_t)(256 + tid) * HID;
    const float* w2p = ow + (size_t)(512 + tid) * HID;
    const float* w3p = ow + (size_t)(768 + tid) * HID;
    for (int ic = 0; ic < HID; ++ic) {
        double w0 = (double)w0p[ic], w1v = (double)w1p[ic], w2v = (double)w2p[ic], w3v = (double)w3p[ic];
        #pragma unroll
        for (int lt = 0; lt < 8; ++lt) {
            double h = (double)hrow[lt][ic];
            a0[lt] += h * w0; a1[lt] += h * w1v; a2[lt] += h * w2v; a3[lt] += h * w3v;
        }
    }
    for (int lt = 0; lt < 8; ++lt) {
        size_t bl = (size_t)b * NF_ + (l0 + lt);
        double gdv = M_PI * tanh(a0[lt]);
        ssc[tid] = gdv;
        __syncthreads();
        for (int off = 1; off < 256; off <<= 1) {
            double v = (tid >= off) ? ssc[tid - off] : 0.0;
            __syncthreads();
            ssc[tid] += v;
            __syncthreads();
        }
        phi[bl * 256 + tid] = (float)ssc[tid];
        __syncthreads();
        srcspec[bl * 512 + tid] = (float)exp(a1[lt]);
        srcspec[bl * 512 + 256 + tid] = (float)exp(a2[lt]);
        nspec[bl * 256 + tid] = (float)(exp(a3[lt]) * (1.0 / 128.0));
    }
}

// allpass IR: irfft(exp(i*phi)) (510) rolled 255. f32 rotation + f64 carrier reseed /16.
__global__ __launch_bounds__(256) void cs8_ir_allpass(const float* __restrict__ phi, float* __restrict__ ir1) {
    __shared__ float cph[256], sph[256];
    size_t bl = blockIdx.x;
    int tid = threadIdx.x;
    {
        float ph = phi[bl * 256 + tid];
        cph[tid] = 2.0f * cosf(ph); sph[tid] = 2.0f * sinf(ph);
    }
    __syncthreads();
    for (int t = tid; t < 510; t += 256) {
        double ang = 2.0 * M_PI * (double)t / 510.0;
        double srd_, crd; sincos(ang, &srd_, &crd);
        double sj, cj;    sincos(16.0 * ang, &sj, &cj);
        float crf = (float)crd, srf = (float)srd_;
        double cD = crd, sD = srd_;
        float acc = 0.5f * (cph[0] + ((t & 1) ? -cph[255] : cph[255]));
        for (int k0 = 1; k0 <= 254; k0 += 16) {
            float c = (float)cD, s = (float)sD;
            int ke = min(k0 + 16, 255);
            for (int k = k0; k < ke; ++k) {
                acc += cph[k] * c - sph[k] * s;
                float cn = c * crf - s * srf;
                float sn = s * crf + c * srf;
                c = cn; s = sn;
            }
            double nc = cD * cj - sD * sj;
            double ns = sD * cj + cD * sj;
            cD = nc; sD = ns;
        }
        int j = t + 255; if (j >= 510) j -= 510;
        ir1[bl * 510 + j] = acc * (1.0f / 510.0f);
    }
}

// half-width window — w=(j-511)/hw; if (w>1) w:=0 (argument zeroed -> win 1)
__device__ __forceinline__ float cs8_hw_win(int j, float hw) {
    float wv = (float)(j - 511) / hw;
    if (wv > 1.0f) wv = 0.0f;
    return (1.0f + cosf((float)M_PI * wv)) * 0.5f;
}

__global__ __launch_bounds__(256) void cs8_ir_src(const float* __restrict__ srcspec,
        const float* __restrict__ f0f, float* __restrict__ ir2) {
    __shared__ float sp[512];
    size_t bl = blockIdx.x;
    int b = blockIdx.x / NF_, l = blockIdx.x % NF_;
    int tid = threadIdx.x;
    sp[tid] = 2.0f * srcspec[bl * 512 + tid];
    sp[tid + 256] = 2.0f * srcspec[bl * 512 + 256 + tid];
    __syncthreads();
    float hw = 66150.0f / (f0f[b * NF_ + l] + 0.001f);
    for (int t = tid; t < 512; t += 256) {
        double ang = 2.0 * M_PI * (double)t / 1022.0;
        double srd_, crd; sincos(ang, &srd_, &crd);
        double sj, cj;    sincos(16.0 * ang, &sj, &cj);
        float crf = (float)crd, srf = (float)srd_;
        double cD = crd, sD = srd_;
        float acc = 0.5f * (sp[0] + ((t & 1) ? -sp[511] : sp[511]));
        for (int k0 = 1; k0 <= 510; k0 += 16) {
            float c = (float)cD, s = (float)sD;
            int ke = min(k0 + 16, 511);
            for (int k = k0; k < ke; ++k) {
                acc += sp[k] * c;
                float cn = c * crf - s * srf;
                float sn = s * crf + c * srf;
                c = cn; s = sn;
            }
            double nc = cD * cj - sD * sj;
            double ns = sD * cj + cD * sj;
            cD = nc; sD = ns;
        }
        float raw = acc * (1.0f / 1022.0f);
        {
            int j = t + 511; if (j >= 1022) j -= 1022;
            ir2[bl * 1022 + j] = raw * cs8_hw_win(j, hw);
        }
        if (t >= 1 && t <= 510) {
            int j = 511 - t;
            ir2[bl * 1022 + j] = raw * cs8_hw_win(j, hw);
        }
    }
}

__global__ __launch_bounds__(256) void cs8_ir_noise(const float* __restrict__ nspec, float* __restrict__ ir3) {
    __shared__ float sp[256];
    size_t bl = blockIdx.x;
    int t = threadIdx.x;
    sp[t] = 2.0f * nspec[bl * 256 + t];
    __syncthreads();
    double ang = 2.0 * M_PI * (double)t / 510.0;
    double srd_, crd; sincos(ang, &srd_, &crd);
    double sj, cj;    sincos(16.0 * ang, &sj, &cj);
    float crf = (float)crd, srf = (float)srd_;
    double cD = crd, sD = srd_;
    float acc = 0.5f * (sp[0] + ((t & 1) ? -sp[255] : sp[255]));
    for (int k0 = 1; k0 <= 254; k0 += 16) {
        float c = (float)cD, s = (float)sD;
        int ke = min(k0 + 16, 255);
        for (int k = k0; k < ke; ++k) {
            acc += sp[k] * c;
            float cn = c * crf - s * srf;
            float sn = s * crf + c * srf;
            c = cn; s = sn;
        }
        double nc = cD * cj - sD * sj;
        double ns = sD * cj + cD * sj;
        cD = nc; sD = ns;
    }
    float raw = acc * (1.0f / 510.0f);
    {
        int j = t + 255; if (j >= 510) j -= 510;
        float win = 0.5f - 0.5f * cosf((float)(2.0 * M_PI) * (float)j / 510.0f);
        ir3[bl * 510 + j] = raw * win;
    }
    if (t >= 1 && t <= 254) {
        int j = 255 - t;
        float win = 0.5f - 0.5f * cosf((float)(2.0 * M_PI) * (float)j / 510.0f);
        ir3[bl * 510 + j] = raw * win;
    }
}

// stage noise frames: frw[b][m][k] = (unoi*2-1)(idx) * bart(k), zeros elsewhere
__global__ __launch_bounds__(256) void cs8_stagef(const float* __restrict__ audio,
        float* __restrict__ frw, float scale, float shift) {
    int bm = blockIdx.x;
    int b = bm / 401, m = bm % 401;
    int tid = threadIdx.x;
    for (int kk = tid; kk < 1028; kk += 256) {
        float v = 0.0f;
        if (kk < 1024) {
            int idx = (m << 9) + kk - 512;
            if (idx >= 0 && idx < TLEN) {
                float a = audio[(size_t)b * TLEN + idx] * scale + shift;
                float bart = 1.0f - fabsf((float)kk * (1.0f / 512.0f) - 1.0f);
                v = a * bart;
            }
        }
        frw[(size_t)bm * 1028 + kk] = v;
    }
}

// ---------------------------------------------------------------------------
// OLA convolution v3: frames pre-windowed in GLOBAL (wave-uniform s_load),
// reversed IR in LDS with XOR bank swizzle, 8 outputs/thread, sliding 3-reg
// window, 32 FMA per sliding b128. FOUT=0: sample output; FOUT=1: write
// bart-windowed frames (for the cascaded conv2 stage).
// ---------------------------------------------------------------------------
__device__ __forceinline__ int cs8_swz(int B) { return B ^ ((B >> 3) & 7); }

__device__ __forceinline__ void cs8_fma8(const float4 F, const float4 A,
        const float4 B, const float4 C, float acc[8]) {
    const float w[12] = {A.x,A.y,A.z,A.w,B.x,B.y,B.z,B.w,C.x,C.y,C.z,C.w};
    #pragma unroll
    for (int a = 0; a < 8; ++a)
        acc[a] += F.x * w[8 - a] + F.y * w[9 - a] + F.z * w[10 - a] + F.w * w[11 - a];
}

template<int IRS, int NFRM, int MOFF, int FOUT>
__global__ __launch_bounds__(256) void cs8_conv(const float* __restrict__ frw,
        const float* __restrict__ ir, float* __restrict__ out) {
    constexpr int PAD = 515;
    constexpr int R = IRS - 1 + PAD;           // 1536 (1022) / 1024 (510); = 0 mod 4
    constexpr int W = (R + 526) & ~3;          // 2060 / 1548
    __shared__ __align__(16) float sir[NFRM][W];
    int b = blockIdx.x / 100, q = blockIdx.x % 100;
    int t0 = q * 2048;
    int m_lo = (t0 >> 9) + MOFF;
    int tid = threadIdx.x;

    // stage reversed IR with XOR swizzle; pads (j outside [0,IRS)) are zero
    for (int i = tid; i < NFRM * W; i += 256) {
        int fi = i / W, x = i - fi * W;
        int j = R - x;
        int m = m_lo + fi;
        float v = 0.0f;
        if (j >= 0 && j < IRS && m >= 0 && m <= 400)
            v = ir[((size_t)b * NF_ + min(m, 399)) * IRS + j];
        int p = (cs8_swz(x >> 2) << 2) | (x & 3);
        sir[fi][p] = v;
    }
    __syncthreads();

    int tb = t0 + tid * 8;
    int wt0 = tid & ~63;
    float acc[8] = {0, 0, 0, 0, 0, 0, 0, 0};
    #pragma unroll
    for (int fi = 0; fi < NFRM; ++fi) {
        int m = m_lo + fi;
        if (m < 0 || m > 400) continue;
        int d0w = t0 + wt0 * 8 + 512 - (m << 9);          // wave-uniform lane-0 d0
        int klo = max(0, d0w - (IRS - 1));
        int khi = min(1023, d0w + 511);
        if (klo > khi) continue;
        int kcs = __builtin_amdgcn_readfirstlane(klo & ~3);
        int nch = ((__builtin_amdgcn_readfirstlane(khi) - kcs) >> 2) + 1;
        int d0 = t0 + tid * 8 + 512 - (m << 9);
        int Bb = (R - d0 + kcs - 8) >> 2;                 // per-lane block base
        const float4* row4 = (const float4*)&sir[fi][0];
        const float4* fp4 = (const float4*)(frw + (size_t)(b * 401 + m) * 1028 + kcs);
        float4 r0 = row4[cs8_swz(Bb)];
        float4 r1 = row4[cs8_swz(Bb + 1)];
        float4 r2;
        int c = 0;
        for (; c + 3 <= nch; c += 3) {
            float4 F0 = fp4[c];
            r2 = row4[cs8_swz(Bb + c + 2)];
            cs8_fma8(F0, r0, r1, r2, acc);
            float4 F1 = fp4[c + 1];
            r0 = row4[cs8_swz(Bb + c + 3)];
            cs8_fma8(F1, r1, r2, r0, acc);
            float4 F2 = fp4[c + 2];
            r1 = row4[cs8_swz(Bb + c + 4)];
            cs8_fma8(F2, r2, r0, r1, acc);
        }
        for (; c < nch; ++c) {
            float4 F = fp4[c];
            r2 = row4[cs8_swz(Bb + c + 2)];
            cs8_fma8(F, r0, r1, r2, acc);
            r0 = r1; r1 = r2;
        }
    }
    if (FOUT == 0) {
        float* o = out + (size_t)b * TLEN + tb;
        *(float4*)o = make_float4(acc[0], acc[1], acc[2], acc[3]);
        *(float4*)(o + 4) = make_float4(acc[4], acc[5], acc[6], acc[7]);
    } else {
        // write as bart-windowed frames: sample tb+j -> (m1, km+512+j) & (m1+1, km+j)
        int km = tb & 511;                      // == 0 mod 8
        int m1 = tb >> 9;                       // 0..399
        float* r1p = out + (size_t)(b * 401 + m1) * 1028;
        float bw[8];
        #pragma unroll
        for (int j2 = 0; j2 < 8; ++j2) bw[j2] = (float)(km + j2) * (1.0f / 512.0f);
        *(float4*)(r1p + 512 + km) = make_float4(acc[0] * (1.f - bw[0]), acc[1] * (1.f - bw[1]),
                                                 acc[2] * (1.f - bw[2]), acc[3] * (1.f - bw[3]));
        *(float4*)(r1p + 512 + km + 4) = make_float4(acc[4] * (1.f - bw[4]), acc[5] * (1.f - bw[5]),
                                                     acc[6] * (1.f - bw[6]), acc[7] * (1.f - bw[7]));
        float* r2p = r1p + 1028;
        *(float4*)(r2p + km) = make_float4(acc[0] * bw[0], acc[1] * bw[1], acc[2] * bw[2], acc[3] * bw[3]);
        *(float4*)(r2p + km + 4) = make_float4(acc[4] * bw[4], acc[5] * bw[5], acc[6] * bw[6], acc[7] * bw[7]);
    }
}

__global__ void cs8_add(const float* __restrict__ a, const float* __restrict__ b,
                        float* __restrict__ o, int n4) {
    int i = blockIdx.x * blockDim.x + threadIdx.x;
    if (i < n4) {
        float4 x = ((const float4*)a)[i];
        float4 y = ((const float4*)b)[i];
        ((float4*)o)[i] = make_float4(x.x + y.x, x.y + y.y, x.z + y.z, x.w + y.w);
    }
}

extern "C" void kernel_launch(void* const* d_in, const int* in_sizes, int n_in,
                              void* d_out, int out_size, void* d_ws, size_t ws_size,
                              hipStream_t stream) {
    const float* mel   = (const float*)d_in[0];
    const float* f0f   = (const float*)d_in[1];
    const float* ip    = (const float*)d_in[2];
    const float* unoi  = (const float*)d_in[3];
    const float* w1    = (const float*)d_in[4];
    const float* b1    = (const float*)d_in[5];
    const float* gng   = (const float*)d_in[6];
    const float* gnb   = (const float*)d_in[7];
    const float* w2    = (const float*)d_in[8];
    const float* b2    = (const float*)d_in[9];
    const float* pw    = (const float*)d_in[10];
    const float* pb    = (const float*)d_in[11];
    const float* lng   = (const float*)d_in[12];
    const float* lnb   = (const float*)d_in[13];
    const float* ow    = (const float*)d_in[14];
    const float* ob    = (const float*)d_in[15];
    float* out = (float*)d_out;
    float* ws  = (float*)d_ws;

    float*  frA  = ws + OFF_A;
    float*  frJ  = ws + OFF_JN;
    float*  h1   = ws + OFF_JN;            // early-phase aliases inside frJ region
    float*  h2   = ws + OFF_JN + S_;
    float*  phi  = ws + OFF_JN + 2 * S_;
    float*  nsp  = ws + OFF_JN + 3 * S_;
    float*  ssp  = ws + OFF_SSP;
    float*  ir1  = ws + OFF_IR1;
    float*  ir3  = ws + OFF_IR3;
    float*  ir2  = ws + OFF_A;             // overwrites frA after conv1 consumes it
    double* fsum = (double*)(ws + OFF_FSUM);
    double* pref = (double*)(ws + OFF_PREF);
    float*  gn   = ws + OFF_GN;

    float* out_sig   = out;
    float* out_phase = out + (size_t)BATCH * TLEN;
    float* out_harm  = out_phase + BATCH * NF_;
    float* out_noise = out_harm + (size_t)BATCH * TLEN;

    hipMemsetAsync(frA, 0, FRSZ * sizeof(float), stream);
    cs8_fsum<<<25, 256, 0, stream>>>(f0f, fsum);
    cs8_prefix<<<1, 16, 0, stream>>>(fsum, pref);
    cs8_phase<<<BATCH * NF_, 512, 0, stream>>>(f0f, ip, pref, frA, out_phase);
    cs8_conv1x3<<<BATCH * NF_, 256, 0, stream>>>(mel, w1, b1, h1);
    cs8_gnstats<<<64, 256, 0, stream>>>(h1, gn);
    cs8_conv2ln<<<BATCH * 50, 256, 0, stream>>>(h1, gn, gng, gnb, w2, b2, pw, pb, lng, lnb, out_phase, h2);
    cs8_proj<<<BATCH * 50, 256, 0, stream>>>(h2, ow, ob, phi, ssp, nsp);
    cs8_ir_allpass<<<BATCH * NF_, 256, 0, stream>>>(phi, ir1);
    cs8_ir_noise<<<BATCH * NF_, 256, 0, stream>>>(nsp, ir3);
    cs8_stagef<<<BATCH * 401, 256, 0, stream>>>(unoi, frJ, 2.0f, -1.0f);
    cs8_conv<510, 6, -1, 0><<<BATCH * 100, 256, 0, stream>>>(frJ, ir3, out_noise);
    hipMemsetAsync(frJ, 0, FRSZ * sizeof(float), stream);
    cs8_conv<510, 6, -1, 1><<<BATCH * 100, 256, 0, stream>>>(frA, ir1, frJ);   // htmp as frames
    cs8_ir_src<<<BATCH * NF_, 256, 0, stream>>>(ssp, f0f, ir2);                // ir2 over dead frA
    cs8_conv<1022, 7, -2, 0><<<BATCH * 100, 256, 0, stream>>>(frJ, ir2, out_harm);
    cs8_add<<<(BATCH * TLEN / 4 + 255) / 256, 256, 0, stream>>>(out_harm, out_noise, out_sig, BATCH * TLEN / 4);
}

// Round 11
// 2713.891 us; speedup vs baseline: 1.0514x; 1.0387x over previous
//
#include <hip/hip_runtime.h>
#include <math.h>

#define BATCH 16
#define NF_ 400
#define TLEN 204800
#define NMELS 80
#define HID 256
#define SRD 44100.0

// ---- workspace layout (floats) ---- (identical to R10)
static constexpr size_t S_   = 1638400;
static constexpr size_t FRSZ = (size_t)6416 * 1028;
static constexpr size_t OFF_A    = 0;
static constexpr size_t OFF_JN   = FRSZ;
static constexpr size_t OFF_SSP  = 2 * FRSZ;
static constexpr size_t OFF_IR1  = OFF_SSP + 2 * S_;
static constexpr size_t OFF_IR3  = OFF_IR1 + 3264000;
static constexpr size_t OFF_FSUM = OFF_IR3 + 3264000;
static constexpr size_t OFF_PREF = OFF_FSUM + 12800;
static constexpr size_t OFF_GN   = OFF_PREF + 12800;

__device__ __forceinline__ float cs9_f0_at(const float* f0f, int b, int n, int k) {
    float a = f0f[b * NF_ + n];
    float c = f0f[b * NF_ + min(n + 1, NF_ - 1)];
    float w = (float)k * (1.0f / 512.0f);
    return __fadd_rn(__fmul_rn(a, 1.0f - w), __fmul_rn(c, w));
}

__global__ void cs9_fsum(const float* __restrict__ f0f, double* __restrict__ fsum) {
    int gid = blockIdx.x * blockDim.x + threadIdx.x;
    if (gid >= BATCH * NF_) return;
    int b = gid / NF_, n = gid % NF_;
    double s = 0.0;
    for (int k = 0; k < 512; ++k) s += (double)cs9_f0_at(f0f, b, n, k) / SRD;
    fsum[gid] = s;
}

__global__ void cs9_prefix(const double* __restrict__ fsum, double* __restrict__ pref) {
    int b = threadIdx.x;
    if (b >= BATCH) return;
    double run = 0.0;
    for (int n = 0; n < NF_; ++n) { pref[b * NF_ + n] = run; run += fsum[b * NF_ + n]; }
}

__global__ __launch_bounds__(512) void cs9_phase(const float* __restrict__ f0f,
        const float* __restrict__ ip, const double* __restrict__ pref,
        float* __restrict__ frA, float* __restrict__ phase_out) {
    __shared__ double sc[512];
    int b = blockIdx.x / NF_, n = blockIdx.x % NF_;
    int k = threadIdx.x;
    float f0 = cs9_f0_at(f0f, b, n, k);
    sc[k] = (double)f0 / SRD;
    __syncthreads();
    for (int off = 1; off < 512; off <<= 1) {
        double v = (k >= off) ? sc[k - off] : 0.0;
        __syncthreads();
        sc[k] += v;
        __syncthreads();
    }
    double xd = pref[b * NF_ + n] + sc[k] + (double)ip[b] / (2.0 * M_PI);
    xd -= rint(xd);
    float xf = (float)xd;
    double zd = 44100.0 * (double)xf / ((double)f0 + 0.001);
    double pz = M_PI * zd;
    float cv = (zd == 0.0) ? 1.0f : (float)(sin(pz) / pz);
    float wb = (float)k * (1.0f / 512.0f);
    size_t row = (size_t)(b * 401 + n) * 1028;
    frA[row + 512 + k]  = cv * (1.0f - wb);
    frA[row + 1028 + k] = cv * wb;
    if (k == 0) phase_out[b * NF_ + n] = (float)(2.0 * M_PI * (double)xf);
}

__global__ __launch_bounds__(256) void cs9_conv1x3(const float* __restrict__ mel,
        const float* __restrict__ w1, const float* __restrict__ b1, float* __restrict__ h1) {
    __shared__ float m3[3][NMELS];
    int b = blockIdx.x / NF_, l = blockIdx.x % NF_;
    int tid = threadIdx.x;
    for (int i = tid; i < 3 * NMELS; i += 256) {
        int tap = i / NMELS, ic = i % NMELS;
        int li = l + tap - 1;
        m3[tap][ic] = (li >= 0 && li < NF_) ? mel[((size_t)b * NF_ + li) * NMELS + ic] : 0.0f;
    }
    __syncthreads();
    int oc = tid;
    double acc = (double)b1[oc];
    const float* wp = w1 + (size_t)oc * NMELS * 3;
    for (int ic = 0; ic < NMELS; ++ic)
        acc += (double)m3[0][ic] * (double)wp[ic * 3]
             + (double)m3[1][ic] * (double)wp[ic * 3 + 1]
             + (double)m3[2][ic] * (double)wp[ic * 3 + 2];
    h1[((size_t)b * NF_ + l) * HID + oc] = (float)acc;
}

__global__ __launch_bounds__(256) void cs9_gnstats(const float* __restrict__ h1, float* __restrict__ gn) {
    __shared__ double rs[256], rq[256];
    int b = blockIdx.x >> 2, g = blockIdx.x & 3;
    int tid = threadIdx.x;
    double s = 0.0, q = 0.0;
    for (int i = tid; i < 64 * NF_; i += 256) {
        int l = i >> 6, c = g * 64 + (i & 63);
        float v = h1[((size_t)b * NF_ + l) * HID + c];
        s += v; q += (double)v * v;
    }
    rs[tid] = s; rq[tid] = q;
    __syncthreads();
    for (int off = 128; off > 0; off >>= 1) {
        if (tid < off) { rs[tid] += rs[tid + off]; rq[tid] += rq[tid + off]; }
        __syncthreads();
    }
    if (tid == 0) {
        double mu = rs[0] / (64.0 * NF_);
        double var = rq[0] / (64.0 * NF_) - mu * mu;
        gn[blockIdx.x * 2] = (float)mu;
        gn[blockIdx.x * 2 + 1] = (float)(1.0 / sqrt(var + 1e-5));
    }
}

__global__ __launch_bounds__(256) void cs9_conv2ln(const float* __restrict__ h1,
        const float* __restrict__ gn, const float* __restrict__ gng, const float* __restrict__ gnb,
        const float* __restrict__ w2, const float* __restrict__ b2,
        const float* __restrict__ pw, const float* __restrict__ pb,
        const float* __restrict__ lng, const float* __restrict__ lnb,
        const float* __restrict__ phase, float* __restrict__ h2) {
    __shared__ float cols[10][HID];
    __shared__ double rsum[256], rsq[256];
    int b = blockIdx.x / 50, l0 = (blockIdx.x % 50) * 8;
    int tid = threadIdx.x;
    for (int i = tid; i < 10 * HID; i += 256) {
        int lc = i >> 8, c = i & 255;
        int l = l0 + lc - 1;
        float v = 0.0f;
        if (l >= 0 && l < NF_) {
            float hv = h1[((size_t)b * NF_ + l) * HID + c];
            int g = c >> 6;
            double vv = ((double)hv - (double)gn[(b * 4 + g) * 2]) * (double)gn[(b * 4 + g) * 2 + 1]
                        * (double)gng[c] + (double)gnb[c];
            v = (float)(vv >= 0.0 ? vv : 0.01 * vv);
        }
        cols[lc][c] = v;
    }
    __syncthreads();
    int oc = tid;
    double acc[8];
    #pragma unroll
    for (int lt = 0; lt < 8; ++lt) acc[lt] = (double)b2[oc];
    const float* wp = w2 + (size_t)oc * HID * 3;
    for (int ic = 0; ic < HID; ++ic) {
        double w0 = (double)wp[ic * 3], w1v = (double)wp[ic * 3 + 1], w2v = (double)wp[ic * 3 + 2];
        float cc[10];
        #pragma unroll
        for (int j = 0; j < 10; ++j) cc[j] = cols[j][ic];
        #pragma unroll
        for (int lt = 0; lt < 8; ++lt)
            acc[lt] += (double)cc[lt] * w0 + (double)cc[lt + 1] * w1v + (double)cc[lt + 2] * w2v;
    }
    for (int lt = 0; lt < 8; ++lt) {
        int l = l0 + lt;
        double ph = (double)phase[b * NF_ + l];
        double sp, cp; sincos(ph, &sp, &cp);
        double v = acc[lt] + sp * (double)pw[oc * 2] + cp * (double)pw[oc * 2 + 1] + (double)pb[oc];
        rsum[tid] = v; rsq[tid] = v * v;
        __syncthreads();
        for (int off = 128; off > 0; off >>= 1) {
            if (tid < off) { rsum[tid] += rsum[tid + off]; rsq[tid] += rsq[tid + off]; }
            __syncthreads();
        }
        double mu = rsum[0] * (1.0 / 256.0);
        double var = rsq[0] * (1.0 / 256.0) - mu * mu;
        double rstd = 1.0 / sqrt(var + 1e-5);
        __syncthreads();
        h2[((size_t)b * NF_ + l) * HID + oc] = (float)((v - mu) * rstd * (double)lng[oc] + (double)lnb[oc]);
    }
}

__global__ __launch_bounds__(256) void cs9_proj(const float* __restrict__ h2,
        const float* __restrict__ ow, const float* __restrict__ ob,
        float* __restrict__ phi, float* __restrict__ srcspec, float* __restrict__ nspec) {
    __shared__ float hrow[8][HID];
    __shared__ double ssc[256];
    int b = blockIdx.x / 50, l0 = (blockIdx.x % 50) * 8;
    int tid = threadIdx.x;
    for (int i = tid; i < 8 * HID; i += 256) {
        int lc = i >> 8, c = i & 255;
        hrow[lc][c] = h2[((size_t)b * NF_ + l0 + lc) * HID + c];
    }
    __syncthreads();
    double a0[8], a1[8], a2[8], a3[8];
    #pragma unroll
    for (int lt = 0; lt < 8; ++lt) {
        a0[lt] = (double)ob[tid];       a1[lt] = (double)ob[256 + tid];
        a2[lt] = (double)ob[512 + tid]; a3[lt] = (double)ob[768 + tid];
    }
    const float* w0p = ow + (size_t)tid * HID;
    const float* w1p = ow + (size_t)(256 + tid) * HID;
    const float* w2p = ow + (size_t)(512 + tid) * HID;
    const float* w3p = ow + (size_t)(768 + tid) * HID;
    for (int ic = 0; ic < HID; ++ic) {
        double w0 = (double)w0p[ic], w1v = (double)w1p[ic], w2v = (double)w2p[ic], w3v = (double)w3p[ic];
        #pragma unroll
        for (int lt = 0; lt < 8; ++lt) {
            double h = (double)hrow[lt][ic];
            a0[lt] += h * w0; a1[lt] += h * w1v; a2[lt] += h * w2v; a3[lt] += h * w3v;
        }
    }
    for (int lt = 0; lt < 8; ++lt) {
        size_t bl = (size_t)b * NF_ + (l0 + lt);
        double gdv = M_PI * tanh(a0[lt]);
        ssc[tid] = gdv;
        __syncthreads();
        for (int off = 1; off < 256; off <<= 1) {
            double v = (tid >= off) ? ssc[tid - off] : 0.0;
            __syncthreads();
            ssc[tid] += v;
            __syncthreads();
        }
        phi[bl * 256 + tid] = (float)ssc[tid];
        __syncthreads();
        srcspec[bl * 512 + tid] = (float)exp(a1[lt]);
        srcspec[bl * 512 + 256 + tid] = (float)exp(a2[lt]);
        nspec[bl * 256 + tid] = (float)(exp(a3[lt]) * (1.0 / 128.0));
    }
}

__global__ __launch_bounds__(256) void cs9_ir_allpass(const float* __restrict__ phi, float* __restrict__ ir1) {
    __shared__ float cph[256], sph[256];
    size_t bl = blockIdx.x;
    int tid = threadIdx.x;
    {
        float ph = phi[bl * 256 + tid];
        cph[tid] = 2.0f * cosf(ph); sph[tid] = 2.0f * sinf(ph);
    }
    __syncthreads();
    for (int t = tid; t < 510; t += 256) {
        double ang = 2.0 * M_PI * (double)t / 510.0;
        double srd_, crd; sincos(ang, &srd_, &crd);
        double sj, cj;    sincos(16.0 * ang, &sj, &cj);
        float crf = (float)crd, srf = (float)srd_;
        double cD = crd, sD = srd_;
        float acc = 0.5f * (cph[0] + ((t & 1) ? -cph[255] : cph[255]));
        for (int k0 = 1; k0 <= 254; k0 += 16) {
            float c = (float)cD, s = (float)sD;
            int ke = min(k0 + 16, 255);
            for (int k = k0; k < ke; ++k) {
                acc += cph[k] * c - sph[k] * s;
                float cn = c * crf - s * srf;
                float sn = s * crf + c * srf;
                c = cn; s = sn;
            }
            double nc = cD * cj - sD * sj;
            double ns = sD * cj + cD * sj;
            cD = nc; sD = ns;
        }
        int j = t + 255; if (j >= 510) j -= 510;
        ir1[bl * 510 + j] = acc * (1.0f / 510.0f);
    }
}

__device__ __forceinline__ float cs9_hw_win(int j, float hw) {
    float wv = (float)(j - 511) / hw;
    if (wv > 1.0f) wv = 0.0f;
    return (1.0f + cosf((float)M_PI * wv)) * 0.5f;
}

__global__ __launch_bounds__(256) void cs9_ir_src(const float* __restrict__ srcspec,
        const float* __restrict__ f0f, float* __restrict__ ir2) {
    __shared__ float sp[512];
    size_t bl = blockIdx.x;
    int b = blockIdx.x / NF_, l = blockIdx.x % NF_;
    int tid = threadIdx.x;
    sp[tid] = 2.0f * srcspec[bl * 512 + tid];
    sp[tid + 256] = 2.0f * srcspec[bl * 512 + 256 + tid];
    __syncthreads();
    float hw = 66150.0f / (f0f[b * NF_ + l] + 0.001f);
    for (int t = tid; t < 512; t += 256) {
        double ang = 2.0 * M_PI * (double)t / 1022.0;
        double srd_, crd; sincos(ang, &srd_, &crd);
        double sj, cj;    sincos(16.0 * ang, &sj, &cj);
        float crf = (float)crd, srf = (float)srd_;
        double cD = crd, sD = srd_;
        float acc = 0.5f * (sp[0] + ((t & 1) ? -sp[511] : sp[511]));
        for (int k0 = 1; k0 <= 510; k0 += 16) {
            float c = (float)cD, s = (float)sD;
            int ke = min(k0 + 16, 511);
            for (int k = k0; k < ke; ++k) {
                acc += sp[k] * c;
                float cn = c * crf - s * srf;
                float sn = s * crf + c * srf;
                c = cn; s = sn;
            }
            double nc = cD * cj - sD * sj;
            double ns = sD * cj + cD * sj;
            cD = nc; sD = ns;
        }
        float raw = acc * (1.0f / 1022.0f);
        {
            int j = t + 511; if (j >= 1022) j -= 1022;
            ir2[bl * 1022 + j] = raw * cs9_hw_win(j, hw);
        }
        if (t >= 1 && t <= 510) {
            int j = 511 - t;
            ir2[bl * 1022 + j] = raw * cs9_hw_win(j, hw);
        }
    }
}

__global__ __launch_bounds__(256) void cs9_ir_noise(const float* __restrict__ nspec, float* __restrict__ ir3) {
    __shared__ float sp[256];
    size_t bl = blockIdx.x;
    int t = threadIdx.x;
    sp[t] = 2.0f * nspec[bl * 256 + t];
    __syncthreads();
    double ang = 2.0 * M_PI * (double)t / 510.0;
    double srd_, crd; sincos(ang, &srd_, &crd);
    double sj, cj;    sincos(16.0 * ang, &sj, &cj);
    float crf = (float)crd, srf = (float)srd_;
    double cD = crd, sD = srd_;
    float acc = 0.5f * (sp[0] + ((t & 1) ? -sp[255] : sp[255]));
    for (int k0 = 1; k0 <= 254; k0 += 16) {
        float c = (float)cD, s = (float)sD;
        int ke = min(k0 + 16, 255);
        for (int k = k0; k < ke; ++k) {
            acc += sp[k] * c;
            float cn = c * crf - s * srf;
            float sn = s * crf + c * srf;
            c = cn; s = sn;
        }
        double nc = cD * cj - sD * sj;
        double ns = sD * cj + cD * sj;
        cD = nc; sD = ns;
    }
    float raw = acc * (1.0f / 510.0f);
    {
        int j = t + 255; if (j >= 510) j -= 510;
        float win = 0.5f - 0.5f * cosf((float)(2.0 * M_PI) * (float)j / 510.0f);
        ir3[bl * 510 + j] = raw * win;
    }
    if (t >= 1 && t <= 254) {
        int j = 255 - t;
        float win = 0.5f - 0.5f * cosf((float)(2.0 * M_PI) * (float)j / 510.0f);
        ir3[bl * 510 + j] = raw * win;
    }
}

__global__ __launch_bounds__(256) void cs9_stagef(const float* __restrict__ audio,
        float* __restrict__ frw, float scale, float shift) {
    int bm = blockIdx.x;
    int b = bm / 401, m = bm % 401;
    int tid = threadIdx.x;
    for (int kk = tid; kk < 1028; kk += 256) {
        float v = 0.0f;
        if (kk < 1024) {
            int idx = (m << 9) + kk - 512;
            if (idx >= 0 && idx < TLEN) {
                float a = audio[(size_t)b * TLEN + idx] * scale + shift;
                float bart = 1.0f - fabsf((float)kk * (1.0f / 512.0f) - 1.0f);
                v = a * bart;
            }
        }
        frw[(size_t)bm * 1028 + kk] = v;
    }
}

// ---------------------------------------------------------------------------
// OLA conv v4: frames AND reversed IR both in LDS. OUTS=4 (conv1022, natural
// 16B-stride conflict-free) or OUTS=8 (conv510, XOR-swizzled). Named-register
// FMA; F read is wave-uniform LDS broadcast.
// ---------------------------------------------------------------------------
__device__ __forceinline__ int cs9_swz(int B) { return B ^ ((B >> 3) & 7); }

template<int IRS, int NFRM, int MOFF, int OUTS, int FOUT>
__global__ __launch_bounds__(256) void cs9_conv(const float* __restrict__ frw,
        const float* __restrict__ ir, float* __restrict__ out) {
    constexpr int TILE = 256 * OUTS;                 // 1024 or 2048
    constexpr int R = IRS + (OUTS == 8 ? 514 : 266); // mod 4 == 0
    constexpr int W = (R + (OUTS == 8 ? 515 : 259) + 3) & ~3;
    __shared__ __align__(16) float sir[NFRM][W];
    __shared__ __align__(16) float sfr[NFRM][1028];
    int b = blockIdx.x / (TLEN / TILE), q = blockIdx.x % (TLEN / TILE);
    int t0 = q * TILE;
    int m_lo = (t0 >> 9) + MOFF;
    int tid = threadIdx.x;

    // stage reversed IR (swizzled iff OUTS==8); pads zero
    for (int i = tid; i < NFRM * W; i += 256) {
        int fi = i / W, x = i - fi * W;
        int j = R - x;
        int m = m_lo + fi;
        float v = 0.0f;
        if (j >= 0 && j < IRS && m >= 0 && m <= 400)
            v = ir[((size_t)b * NF_ + min(m, 399)) * IRS + j];
        int p = (OUTS == 8) ? ((cs9_swz(x >> 2) << 2) | (x & 3)) : x;
        sir[fi][p] = v;
    }
    // stage frames (float4 copy; OOB rows zero)
    for (int i = tid; i < NFRM * 257; i += 256) {
        int fi = i / 257, x4 = i - fi * 257;
        int m = m_lo + fi;
        float4 v = make_float4(0.f, 0.f, 0.f, 0.f);
        if (m >= 0 && m <= 400)
            v = ((const float4*)(frw + (size_t)(b * 401 + m) * 1028))[x4];
        ((float4*)&sfr[fi][0])[x4] = v;
    }
    __syncthreads();

    int tb = t0 + tid * OUTS;
    int wt0 = tid & ~63;
    float acc[OUTS];
    #pragma unroll
    for (int a = 0; a < OUTS; ++a) acc[a] = 0.0f;

    #pragma unroll
    for (int fi = 0; fi < NFRM; ++fi) {
        int m = m_lo + fi;
        if (m < 0 || m > 400) continue;
        int d0w = __builtin_amdgcn_readfirstlane(t0 + wt0 * OUTS + 512 - (m << 9));
        int klo = max(0, d0w - (IRS - 1));
        int khi = min(1023, d0w + 64 * OUTS - 1);
        if (klo > khi) continue;
        int kcs = klo & ~3;
        int nch = ((khi - kcs) >> 2) + 1;
        int d0 = t0 + tid * OUTS + 512 - (m << 9);
        const float4* row4 = (const float4*)&sir[fi][0];
        const float4* fp4 = (const float4*)&sfr[fi][0] + (kcs >> 2);

        if (OUTS == 4) {
            int Bb = (R - d0 + kcs - 4) >> 2;
            float4 A = row4[Bb];
            int c = 0;
            for (; c + 2 <= nch; c += 2) {
                float4 Bv = row4[Bb + c + 1];
                float4 F0 = fp4[c];
                acc[0] += F0.x * Bv.x + F0.y * Bv.y + F0.z * Bv.z + F0.w * Bv.w;
                acc[1] += F0.x * A.w  + F0.y * Bv.x + F0.z * Bv.y + F0.w * Bv.z;
                acc[2] += F0.x * A.z  + F0.y * A.w  + F0.z * Bv.x + F0.w * Bv.y;
                acc[3] += F0.x * A.y  + F0.y * A.z  + F0.z * A.w  + F0.w * Bv.x;
                float4 A2 = row4[Bb + c + 2];
                float4 F1 = fp4[c + 1];
                acc[0] += F1.x * A2.x + F1.y * A2.y + F1.z * A2.z + F1.w * A2.w;
                acc[1] += F1.x * Bv.w + F1.y * A2.x + F1.z * A2.y + F1.w * A2.z;
                acc[2] += F1.x * Bv.z + F1.y * Bv.w + F1.z * A2.x + F1.w * A2.y;
                acc[3] += F1.x * Bv.y + F1.y * Bv.z + F1.z * Bv.w + F1.w * A2.x;
                A = A2;
            }
            for (; c < nch; ++c) {
                float4 Bv = row4[Bb + c + 1];
                float4 F0 = fp4[c];
                acc[0] += F0.x * Bv.x + F0.y * Bv.y + F0.z * Bv.z + F0.w * Bv.w;
                acc[1] += F0.x * A.w  + F0.y * Bv.x + F0.z * Bv.y + F0.w * Bv.z;
                acc[2] += F0.x * A.z  + F0.y * A.w  + F0.z * Bv.x + F0.w * Bv.y;
                acc[3] += F0.x * A.y  + F0.y * A.z  + F0.z * A.w  + F0.w * Bv.x;
                A = Bv;
            }
        } else {
            int Bb = (R - d0 + kcs - 8) >> 2;
            float4 A = row4[cs9_swz(Bb)];
            float4 Bv = row4[cs9_swz(Bb + 1)];
            float4 C;
            int c = 0;
            for (; c + 3 <= nch; c += 3) {
                float4 F0 = fp4[c];
                C = row4[cs9_swz(Bb + c + 2)];
                acc[0] += F0.x*C.x + F0.y*C.y + F0.z*C.z + F0.w*C.w;
                acc[1] += F0.x*Bv.w + F0.y*C.x + F0.z*C.y + F0.w*C.z;
                acc[2] += F0.x*Bv.z + F0.y*Bv.w + F0.z*C.x + F0.w*C.y;
                acc[3] += F0.x*Bv.y + F0.y*Bv.z + F0.z*Bv.w + F0.w*C.x;
                acc[4] += F0.x*Bv.x + F0.y*Bv.y + F0.z*Bv.z + F0.w*Bv.w;
                acc[5] += F0.x*A.w + F0.y*Bv.x + F0.z*Bv.y + F0.w*Bv.z;
                acc[6] += F0.x*A.z + F0.y*A.w + F0.z*Bv.x + F0.w*Bv.y;
                acc[7] += F0.x*A.y + F0.y*A.z + F0.z*A.w + F0.w*Bv.x;
                float4 F1 = fp4[c + 1];
                A = row4[cs9_swz(Bb + c + 3)];
                acc[0] += F1.x*A.x + F1.y*A.y + F1.z*A.z + F1.w*A.w;
                acc[1] += F1.x*C.w + F1.y*A.x + F1.z*A.y + F1.w*A.z;
                acc[2] += F1.x*C.z + F1.y*C.w + F1.z*A.x + F1.w*A.y;
                acc[3] += F1.x*C.y + F1.y*C.z + F1.z*C.w + F1.w*A.x;
                acc[4] += F1.x*C.x + F1.y*C.y + F1.z*C.z + F1.w*C.w;
                acc[5] += F1.x*Bv.w + F1.y*C.x + F1.z*C.y + F1.w*C.z;
                acc[6] += F1.x*Bv.z + F1.y*Bv.w + F1.z*C.x + F1.w*C.y;
                acc[7] += F1.x*Bv.y + F1.y*Bv.z + F1.z*Bv.w + F1.w*C.x;
                float4 F2 = fp4[c + 2];
                Bv = row4[cs9_swz(Bb + c + 4)];
                acc[0] += F2.x*Bv.x + F2.y*Bv.y + F2.z*Bv.z + F2.w*Bv.w;
                acc[1] += F2.x*A.w + F2.y*Bv.x + F2.z*Bv.y + F2.w*Bv.z;
                acc[2] += F2.x*A.z + F2.y*A.w + F2.z*Bv.x + F2.w*Bv.y;
                acc[3] += F2.x*A.y + F2.y*A.z + F2.z*A.w + F2.w*Bv.x;
                acc[4] += F2.x*A.x + F2.y*A.y + F2.z*A.z + F2.w*A.w;
                acc[5] += F2.x*C.w + F2.y*A.x + F2.z*A.y + F2.w*A.z;
                acc[6] += F2.x*C.z + F2.y*C.w + F2.z*A.x + F2.w*A.y;
                acc[7] += F2.x*C.y + F2.y*C.z + F2.z*C.w + F2.w*A.x;
            }
            for (; c < nch; ++c) {
                float4 F0 = fp4[c];
                C = row4[cs9_swz(Bb + c + 2)];
                acc[0] += F0.x*C.x + F0.y*C.y + F0.z*C.z + F0.w*C.w;
                acc[1] += F0.x*Bv.w + F0.y*C.x + F0.z*C.y + F0.w*C.z;
                acc[2] += F0.x*Bv.z + F0.y*Bv.w + F0.z*C.x + F0.w*C.y;
                acc[3] += F0.x*Bv.y + F0.y*Bv.z + F0.z*Bv.w + F0.w*C.x;
                acc[4] += F0.x*Bv.x + F0.y*Bv.y + F0.z*Bv.z + F0.w*Bv.w;
                acc[5] += F0.x*A.w + F0.y*Bv.x + F0.z*Bv.y + F0.w*Bv.z;
                acc[6] += F0.x*A.z + F0.y*A.w + F0.z*Bv.x + F0.w*Bv.y;
                acc[7] += F0.x*A.y + F0.y*A.z + F0.z*A.w + F0.w*Bv.x;
                A = Bv; Bv = C;
            }
        }
    }

    if (FOUT == 0) {
        float* o = out + (size_t)b * TLEN + tb;
        #pragma unroll
        for (int a4 = 0; a4 < OUTS; a4 += 4)
            *(float4*)(o + a4) = make_float4(acc[a4], acc[a4+1], acc[a4+2], acc[a4+3]);
    } else {
        int km = tb & 511;
        int m1 = tb >> 9;
        float* r1p = out + (size_t)(b * 401 + m1) * 1028;
        float* r2p = r1p + 1028;
        float bw[OUTS];
        #pragma unroll
        for (int j2 = 0; j2 < OUTS; ++j2) bw[j2] = (float)(km + j2) * (1.0f / 512.0f);
        #pragma unroll
        for (int a4 = 0; a4 < OUTS; a4 += 4) {
            *(float4*)(r1p + 512 + km + a4) = make_float4(
                acc[a4] * (1.f - bw[a4]), acc[a4+1] * (1.f - bw[a4+1]),
                acc[a4+2] * (1.f - bw[a4+2]), acc[a4+3] * (1.f - bw[a4+3]));
            *(float4*)(r2p + km + a4) = make_float4(
                acc[a4] * bw[a4], acc[a4+1] * bw[a4+1],
                acc[a4+2] * bw[a4+2], acc[a4+3] * bw[a4+3]);
        }
    }
}

__global__ void cs9_add(const float* __restrict__ a, const float* __restrict__ b,
                        float* __restrict__ o, int n4) {
    int i = blockIdx.x * blockDim.x + threadIdx.x;
    if (i < n4) {
        float4 x = ((const float4*)a)[i];
        float4 y = ((const float4*)b)[i];
        ((float4*)o)[i] = make_float4(x.x + y.x, x.y + y.y, x.z + y.z, x.w + y.w);
    }
}

extern "C" void kernel_launch(void* const* d_in, const int* in_sizes, int n_in,
                              void* d_out, int out_size, void* d_ws, size_t ws_size,
                              hipStream_t stream) {
    const float* mel   = (const float*)d_in[0];
    const float* f0f   = (const float*)d_in[1];
    const float* ip    = (const float*)d_in[2];
    const float* unoi  = (const float*)d_in[3];
    const float* w1    = (const float*)d_in[4];
    const float* b1    = (const float*)d_in[5];
    const float* gng   = (const float*)d_in[6];
    const float* gnb   = (const float*)d_in[7];
    const float* w2    = (const float*)d_in[8];
    const float* b2    = (const float*)d_in[9];
    const float* pw    = (const float*)d_in[10];
    const float* pb    = (const float*)d_in[11];
    const float* lng   = (const float*)d_in[12];
    const float* lnb   = (const float*)d_in[13];
    const float* ow    = (const float*)d_in[14];
    const float* ob    = (const float*)d_in[15];
    float* out = (float*)d_out;
    float* ws  = (float*)d_ws;

    float*  frA  = ws + OFF_A;
    float*  frJ  = ws + OFF_JN;
    float*  h1   = ws + OFF_JN;
    float*  h2   = ws + OFF_JN + S_;
    float*  phi  = ws + OFF_JN + 2 * S_;
    float*  nsp  = ws + OFF_JN + 3 * S_;
    float*  ssp  = ws + OFF_SSP;
    float*  ir1  = ws + OFF_IR1;
    float*  ir3  = ws + OFF_IR3;
    float*  ir2  = ws + OFF_A;
    double* fsum = (double*)(ws + OFF_FSUM);
    double* pref = (double*)(ws + OFF_PREF);
    float*  gn   = ws + OFF_GN;

    float* out_sig   = out;
    float* out_phase = out + (size_t)BATCH * TLEN;
    float* out_harm  = out_phase + BATCH * NF_;
    float* out_noise = out_harm + (size_t)BATCH * TLEN;

    hipMemsetAsync(frA, 0, FRSZ * sizeof(float), stream);
    cs9_fsum<<<25, 256, 0, stream>>>(f0f, fsum);
    cs9_prefix<<<1, 16, 0, stream>>>(fsum, pref);
    cs9_phase<<<BATCH * NF_, 512, 0, stream>>>(f0f, ip, pref, frA, out_phase);
    cs9_conv1x3<<<BATCH * NF_, 256, 0, stream>>>(mel, w1, b1, h1);
    cs9_gnstats<<<64, 256, 0, stream>>>(h1, gn);
    cs9_conv2ln<<<BATCH * 50, 256, 0, stream>>>(h1, gn, gng, gnb, w2, b2, pw, pb, lng, lnb, out_phase, h2);
    cs9_proj<<<BATCH * 50, 256, 0, stream>>>(h2, ow, ob, phi, ssp, nsp);
    cs9_ir_allpass<<<BATCH * NF_, 256, 0, stream>>>(phi, ir1);
    cs9_ir_noise<<<BATCH * NF_, 256, 0, stream>>>(nsp, ir3);
    cs9_stagef<<<BATCH * 401, 256, 0, stream>>>(unoi, frJ, 2.0f, -1.0f);
    cs9_conv<510, 6, -1, 8, 0><<<BATCH * 100, 256, 0, stream>>>(frJ, ir3, out_noise);
    hipMemsetAsync(frJ, 0, FRSZ * sizeof(float), stream);
    cs9_conv<510, 6, -1, 8, 1><<<BATCH * 100, 256, 0, stream>>>(frA, ir1, frJ);
    cs9_ir_src<<<BATCH * NF_, 256, 0, stream>>>(ssp, f0f, ir2);
    cs9_conv<1022, 5, -2, 4, 0><<<BATCH * 200, 256, 0, stream>>>(frJ, ir2, out_harm);
    cs9_add<<<(BATCH * TLEN / 4 + 255) / 256, 256, 0, stream>>>(out_harm, out_noise, out_sig, BATCH * TLEN / 4);
}